// Round 14
// baseline (133.600 us; speedup 1.0000x reference)
//
#include <hip/hip_runtime.h>

#define DI __device__ __forceinline__

typedef _Float16 f16x8 __attribute__((ext_vector_type(8)));
typedef _Float16 f16x4 __attribute__((ext_vector_type(4)));
typedef float    f32x4 __attribute__((ext_vector_type(4)));

namespace {

constexpr int kB  = 8;
constexpr int kMQ = 512;
constexpr int kMK = 2048;
constexpr int kQKC = 1024;   // = H*DQ
constexpr int kVC  = 1024;   // = H*DV

DI void gload16(const void* g, void* l) {
  __builtin_amdgcn_global_load_lds(
      (const __attribute__((address_space(1))) void*)g,
      (__attribute__((address_space(3))) void*)l, 16, 0, 0);
}

DI f32x4 mfma16(f16x8 a, f16x8 b, f32x4 c) {
  return __builtin_amdgcn_mfma_f32_16x16x32_f16(a, b, c, 0, 0, 0);
}

DI f32x4 mfma16k16(f16x4 a, f16x4 b, f32x4 c) {
  return __builtin_amdgcn_mfma_f32_16x16x16f16(a, b, c, 0, 0, 0);
}

// ================= unified prep: 3 weight transposes + 2 LayerNorms =================
template<int K, int N>
DI void transpose_dev(const float* __restrict__ W, _Float16* __restrict__ WT,
                      int bid, float (*t)[65]) {
  int nt = bid % (N / 64), kt = bid / (N / 64);
  int k0 = kt * 64, n0 = nt * 64;
  int tid = threadIdx.x;
#pragma unroll
  for (int j = 0; j < 16; ++j) {
    int e = tid + j * 256;
    int r = e >> 6, c = e & 63;
    t[r][c] = W[(size_t)(k0 + r) * N + n0 + c];
  }
  __syncthreads();
#pragma unroll
  for (int j = 0; j < 16; ++j) {
    int e = tid + j * 256;
    int r = e >> 6, c = e & 63;
    WT[(size_t)(n0 + r) * K + k0 + c] = (_Float16)t[c][r];
  }
}

DI void ln1024_dev(const float* __restrict__ x, const float* __restrict__ w,
                   const float* __restrict__ bb, _Float16* __restrict__ y,
                   int row, float* red) {
  int tid = threadIdx.x;
  const float4* xr = (const float4*)(x + (size_t)row * 1024);
  float4 v = xr[tid];
  float s = v.x + v.y + v.z + v.w;
  float q = v.x * v.x + v.y * v.y + v.z * v.z + v.w * v.w;
#pragma unroll
  for (int m = 32; m; m >>= 1) { s += __shfl_xor(s, m); q += __shfl_xor(q, m); }
  if ((tid & 63) == 0) { red[tid >> 6] = s; red[4 + (tid >> 6)] = q; }
  __syncthreads();
  s = red[0] + red[1] + red[2] + red[3];
  q = red[4] + red[5] + red[6] + red[7];
  float mean = s * (1.0f / 1024.0f);
  float var = q * (1.0f / 1024.0f) - mean * mean;
  float inv = rsqrtf(var + 1e-5f);
  f16x4 o;
  const float* wp = w + tid * 4;
  const float* bp = bb + tid * 4;
  o[0] = (_Float16)((v.x - mean) * inv * wp[0] + bp[0]);
  o[1] = (_Float16)((v.y - mean) * inv * wp[1] + bp[1]);
  o[2] = (_Float16)((v.z - mean) * inv * wp[2] + bp[2]);
  o[3] = (_Float16)((v.w - mean) * inv * wp[3] + bp[3]);
  *(f16x4*)(y + (size_t)row * 1024 + tid * 4) = o;
}

DI void ln256_dev(const float* __restrict__ x, const float* __restrict__ w,
                  const float* __restrict__ bb, _Float16* __restrict__ y, int bid) {
  int tid = threadIdx.x;
  int lane = tid & 63, wv = tid >> 6;
  size_t row = (size_t)bid * 4 + wv;
  const float4* xr = (const float4*)(x + row * 256);
  float4 v = xr[lane];
  float s = v.x + v.y + v.z + v.w;
  float q = v.x * v.x + v.y * v.y + v.z * v.z + v.w * v.w;
#pragma unroll
  for (int m = 32; m; m >>= 1) { s += __shfl_xor(s, m); q += __shfl_xor(q, m); }
  float mean = s * (1.0f / 256.0f);
  float var = q * (1.0f / 256.0f) - mean * mean;
  float inv = rsqrtf(var + 1e-5f);
  f16x4 o;
  const float* wp = w + lane * 4;
  const float* bp = bb + lane * 4;
  o[0] = (_Float16)((v.x - mean) * inv * wp[0] + bp[0]);
  o[1] = (_Float16)((v.y - mean) * inv * wp[1] + bp[1]);
  o[2] = (_Float16)((v.z - mean) * inv * wp[2] + bp[2]);
  o[3] = (_Float16)((v.w - mean) * inv * wp[3] + bp[3]);
  *(f16x4*)(y + row * 256 + lane * 4) = o;
}

__global__ __launch_bounds__(256) void prep_all(
    const float* __restrict__ Wq, const float* __restrict__ Wk, const float* __restrict__ Wv,
    _Float16* __restrict__ WqT, _Float16* __restrict__ WkT, _Float16* __restrict__ WvT,
    const float* __restrict__ hs, const float* __restrict__ ln1w, const float* __restrict__ ln1b,
    _Float16* __restrict__ hsln,
    const float* __restrict__ xin, const float* __restrict__ ln2w, const float* __restrict__ ln2b,
    _Float16* __restrict__ kvln) {
  __shared__ float tbuf[64][65];
  int bid = blockIdx.x;
  if (bid < 256) {
    transpose_dev<1024, 1024>(Wq, WqT, bid, tbuf);
  } else if (bid < 320) {
    transpose_dev<256, 1024>(Wk, WkT, bid - 256, tbuf);
  } else if (bid < 384) {
    transpose_dev<256, 1024>(Wv, WvT, bid - 320, tbuf);
  } else if (bid < 4480) {
    ln1024_dev(hs, ln1w, ln1b, hsln, bid - 384, (float*)tbuf);
  } else {
    ln256_dev(xin, ln2w, ln2b, kvln, bid - 4480);
  }
}

// ================= unified projection GEMM (CM decode for q/k A-panel L2 reuse) =====
template<int M, int N, int K, bool BIAS_ROW, int MMODE, bool CM>
DI void gemm_dev(const _Float16* __restrict__ A, const _Float16* __restrict__ Bt,
                 const float* __restrict__ bias, const int* __restrict__ msk,
                 _Float16* __restrict__ C, int bid,
                 _Float16 (*As)[128 * 64], _Float16 (*Bs)[128 * 64]) {
  int tid = threadIdx.x, lane = tid & 63;
  int w = tid >> 6, wr = w >> 1, wc = w & 1;
  constexpr int NT = N / 128;
  constexpr int MT = M / 128;
  constexpr int KT = K / 64;
  int mt, nt;
  if constexpr (CM) { mt = bid % MT; nt = bid / MT; }
  else              { mt = bid / NT; nt = bid % NT; }
  if constexpr (MMODE == 1) { if (msk[mt * 128] == 0) return; }
  if constexpr (MMODE == 2) { if (msk[nt * 128] == 0) return; }
  const int l15 = lane & 15, l4 = lane >> 4;

  f32x4 acc[4][4] = {};

  const int rS = tid >> 3;   // staging row (0..31) per 4KB call
  const int cpS = tid & 7;   // staging physical chunk

  auto stage = [&](int kt, int bufi) {
#pragma unroll
    for (int j = 0; j < 4; ++j) {
      int rr = rS + j * 32;
      int cg = cpS ^ (rr & 7);
      gload16(A  + ((size_t)(mt * 128 + rr) * K + kt * 64 + cg * 8),
              (char*)As[bufi] + j * 4096 + tid * 16);
      gload16(Bt + ((size_t)(nt * 128 + rr) * K + kt * 64 + cg * 8),
              (char*)Bs[bufi] + j * 4096 + tid * 16);
    }
  };

  stage(0, 0);
  __syncthreads();

  for (int kt = 0; kt < KT; ++kt) {
    int cur = kt & 1;
    if (kt + 1 < KT) stage(kt + 1, cur ^ 1);
#pragma unroll
    for (int ss = 0; ss < 2; ++ss) {
      f16x8 a[4], b[4];
#pragma unroll
      for (int m = 0; m < 4; ++m) {
        int ra = wr * 64 + m * 16 + l15;
        int cl = ss * 4 + l4;
        a[m] = *(const f16x8*)((const char*)As[cur] + ra * 128 + ((cl ^ (ra & 7)) << 4));
        int rb = wc * 64 + m * 16 + l15;
        b[m] = *(const f16x8*)((const char*)Bs[cur] + rb * 128 + ((cl ^ (rb & 7)) << 4));
      }
#pragma unroll
      for (int m = 0; m < 4; ++m)
#pragma unroll
        for (int n = 0; n < 4; ++n)
          acc[m][n] = mfma16(a[m], b[n], acc[m][n]);
    }
    __syncthreads();
  }

#pragma unroll
  for (int m = 0; m < 4; ++m) {
#pragma unroll
    for (int n = 0; n < 4; ++n) {
      int gi0 = mt * 128 + wr * 64 + m * 16 + l4 * 4;
      int gj  = nt * 128 + wc * 64 + n * 16 + l15;
#pragma unroll
      for (int r = 0; r < 4; ++r) {
        int gi = gi0 + r;
        float v = acc[m][n][r] + (BIAS_ROW ? bias[gi] : bias[gj]);
        C[(size_t)gi * N + gj] = (_Float16)v;
      }
    }
  }
}

__global__ __launch_bounds__(256) void gemm_all(
    const _Float16* __restrict__ hsln, const _Float16* __restrict__ WqT,
    const float* __restrict__ bq, _Float16* __restrict__ qbf,
    const _Float16* __restrict__ kvln, const _Float16* __restrict__ WkT,
    const float* __restrict__ bk, _Float16* __restrict__ kbf,
    const _Float16* __restrict__ WvT, const float* __restrict__ bv,
    _Float16* __restrict__ vT, const int* __restrict__ msk) {
  __shared__ _Float16 As[2][128 * 64];
  __shared__ _Float16 Bs[2][128 * 64];
  int bid = blockIdx.x;
  if (bid < 256) {
    gemm_dev<4096, 1024, 1024, false, 0, true>(hsln, WqT, bq, nullptr, qbf, bid, As, Bs);
  } else if (bid < 1280) {
    gemm_dev<16384, 1024, 256, false, 1, true>(kvln, WkT, bk, msk, kbf, bid - 256, As, Bs);
  } else {
    gemm_dev<1024, 16384, 256, true, 2, false>(WvT, kvln, bv, msk, vT, bid - 1280, As, Bs);
  }
}

// ============ fused masked flash attention (static balanced pairing, 2 items/block) ==
// grid = 256 blocks, 512 thr = 8 waves = 4 q-subtiles (16 rows) x 2 key-groups.
// Work item = (batch, h, qt64); 512 items total. Block -> class c = bid%8 (= h, same
// h->XCD affinity as before), machine m = bid/8, pair pc = m>>3, slot s = m&7.
// Item 1 = batch of length-rank pc, item 2 = batch of rank 7-pc (both qt = s):
// pairing opposite order statistics balances per-block load (~n_max+n_min tiles)
// vs the previous max-batch-bound makespan. All ranks derived from the mask with
// compile-time-indexed unrolled code (no scratch). No atomics, no fences.
__global__ __launch_bounds__(512, 2) void attn_kernel(const _Float16* __restrict__ qm,
                                                      const _Float16* __restrict__ km,
                                                      const _Float16* __restrict__ vT,
                                                      const int* __restrict__ msk,
                                                      float* __restrict__ out) {
  __shared__ _Float16 Ksp[2][64 * 128];   // [key][d] rows 256B; merge scratch after loop
  __shared__ _Float16 Vsp[2][128 * 64];   // [dv][key] rows 128B
  __shared__ float mlb[64][2];            // partner (m,l) per q row

  int tid = threadIdx.x, lane = tid & 63, w = tid >> 6;
  const int l15 = lane & 15, l4 = lane >> 4;
  const int wq = w & 3;        // q-subtile (0..3), rows qt*64 + wq*16 + l15
  const int g  = w >> 2;       // key group (0..1), keys g*32 .. g*32+31

  const int c  = blockIdx.x & 7;    // h class (= XCD affinity class)
  const int m  = blockIdx.x >> 3;   // machine within class [0,32)
  const int pc = m >> 3;            // pair class [0,4)
  const int s  = m & 7;             // qt slot [0,8)
  const int h  = c;

  // per-batch tile counts (prefix mask), all threads redundantly
  int nt0, nt1, nt2, nt3, nt4, nt5, nt6, nt7;
  {
    int nts[8];
#pragma unroll
    for (int bb = 0; bb < 8; ++bb) {
      int vld = (lane < 32) ? msk[bb * kMK + lane * 64] : 0;
      nts[bb] = __popcll(__ballot(vld != 0));
    }
    nt0 = nts[0]; nt1 = nts[1]; nt2 = nts[2]; nt3 = nts[3];
    nt4 = nts[4]; nt5 = nts[5]; nt6 = nts[6]; nt7 = nts[7];
  }
  // rank(bb) = #batches strictly longer (ties by index) — select ranks pc and 7-pc
  int bA = 0, bB = 0, ntA = 0, ntB = 0;
  {
    int nts[8] = {nt0, nt1, nt2, nt3, nt4, nt5, nt6, nt7};
#pragma unroll
    for (int bb = 0; bb < 8; ++bb) {
      int rk = 0;
#pragma unroll
      for (int j = 0; j < 8; ++j)
        rk += (nts[j] > nts[bb]) || (nts[j] == nts[bb] && j < bb);
      if (rk == pc)     { bA = bb; ntA = nts[bb]; }
      if (rk == 7 - pc) { bB = bb; ntB = nts[bb]; }
    }
  }

  const float sl2 = 0.08838834764831845f * 1.4426950408889634f;  // scale * log2(e)

  const int rK = tid >> 4, cpK = tid & 15;   // K staging: 32 rows/call (512 thr)
  const int rV = tid >> 3, cpV = tid & 7;    // V staging: 64 rows/call

#pragma unroll 1
  for (int it = 0; it < 2; ++it) {
    const int b = it == 0 ? bA : bB;
    const int ntiles = it == 0 ? ntA : ntB;
    const int qt = s;

    int lv = msk[b * kMK + (ntiles - 1) * 64 + lane];
    int lastlen = __popcll(__ballot(lv != 0));

    // Q fragments (B-operand): lane holds Q[q=qt*64+wq*16+l15][d=kc*32+l4*8+:8]
    f16x8 qf[4];
#pragma unroll
    for (int kc = 0; kc < 4; ++kc)
      qf[kc] = *(const f16x8*)(qm +
          (size_t)(b * kMQ + qt * 64 + wq * 16 + l15) * kQKC +
          h * 128 + kc * 32 + l4 * 8);

    f32x4 o[8] = {};               // O^T partial (this key group)
    float rm = -1e30f, rl = 0.0f;

    auto stage = [&](int kt, int bufi) {
#pragma unroll
      for (int j = 0; j < 2; ++j) {
        int rr = rK + j * 32;
        int cg = cpK ^ (rr & 7);
        gload16(km + (size_t)(b * kMK + kt * 64 + rr) * kQKC + h * 128 + cg * 8,
                (char*)Ksp[bufi] + j * 8192 + tid * 16);
      }
#pragma unroll
      for (int j = 0; j < 2; ++j) {
        int dv = rV + j * 64;
        int cg = cpV ^ (dv & 7);
        gload16(vT + (size_t)(h * 128 + dv) * (kB * kMK) + (size_t)b * kMK + kt * 64 + cg * 8,
                (char*)Vsp[bufi] + j * 8192 + tid * 16);
      }
    };

    __syncthreads();   // protect Ksp/Vsp from previous item's merge readers
    stage(0, 0);
    __syncthreads();

    for (int kt = 0; kt < ntiles; ++kt) {
      int cur = kt & 1;
      if (kt + 1 < ntiles) stage(kt + 1, cur ^ 1);

      // S^T = mfma(K, Q): sc[kf] = S[key=g*32+kf*16+l4*4+r][q=l15]
      f32x4 sc[2] = {};
      __builtin_amdgcn_s_setprio(1);
#pragma unroll
      for (int kc = 0; kc < 4; ++kc) {
        f16x8 kb[2];
#pragma unroll
        for (int kf = 0; kf < 2; ++kf) {
          int rr = g * 32 + kf * 16 + l15;
          int cl = kc * 4 + l4;
          kb[kf] = *(const f16x8*)((const char*)Ksp[cur] + rr * 256 + ((cl ^ (rr & 7)) << 4));
        }
#pragma unroll
        for (int kf = 0; kf < 2; ++kf)
          sc[kf] = mfma16(kb[kf], qf[kc], sc[kf]);
      }
      __builtin_amdgcn_s_setprio(0);

      // tail mask on the final tile
      if (kt == ntiles - 1) {
#pragma unroll
        for (int kf = 0; kf < 2; ++kf)
#pragma unroll
          for (int r = 0; r < 4; ++r)
            if (g * 32 + kf * 16 + l4 * 4 + r >= lastlen) sc[kf][r] = -3e38f;
      }

      // lane-parallel online softmax (q = l15)
      float mx = sc[0][0];
#pragma unroll
      for (int kf = 0; kf < 2; ++kf)
#pragma unroll
        for (int r = 0; r < 4; ++r) mx = fmaxf(mx, sc[kf][r]);
      mx = fmaxf(mx, __shfl_xor(mx, 16));
      mx = fmaxf(mx, __shfl_xor(mx, 32));
      float al = 1.0f;
      if (__any(mx > rm)) {
        float nm = fmaxf(rm, mx);
        al = __builtin_amdgcn_exp2f((rm - nm) * sl2);
        rm = nm;
#pragma unroll
        for (int n = 0; n < 8; ++n)
#pragma unroll
          for (int r = 0; r < 4; ++r) o[n][r] *= al;
      }
      float nms = rm * sl2;
      float ts = 0.0f;
      f16x4 pb[2];
#pragma unroll
      for (int kf = 0; kf < 2; ++kf)
#pragma unroll
        for (int r = 0; r < 4; ++r) {
          float p = __builtin_amdgcn_exp2f(sc[kf][r] * sl2 - nms);
          pb[kf][r] = (_Float16)p;
          ts += p;
        }
      ts += __shfl_xor(ts, 16);
      ts += __shfl_xor(ts, 32);
      rl = rl * al + ts;

      // O^T += V^T P over this group's keys
      __builtin_amdgcn_s_setprio(1);
#pragma unroll
      for (int n = 0; n < 8; ++n) {
        int dv = n * 16 + l15;
#pragma unroll
        for (int kf = 0; kf < 2; ++kf) {
          int phys = (g * 4 + kf * 2 + (l4 >> 1)) ^ (dv & 7);
          f16x4 vb = *(const f16x4*)((const char*)Vsp[cur] +
                                     dv * 128 + (phys << 4) + (l4 & 1) * 8);
          o[n] = mfma16k16(vb, pb[kf], o[n]);
        }
      }
      __builtin_amdgcn_s_setprio(0);
      __syncthreads();
    }

    // ===== intra-block merge of the two key-groups (LDS, no fences) =====
    float* Mbuf = (float*)Ksp;   // 64 q x 128 dv f32 = 32KB (K buffers dead)
    if (g == 1) {
#pragma unroll
      for (int n = 0; n < 8; ++n)
#pragma unroll
        for (int r = 0; r < 4; ++r)
          Mbuf[(n * 16 + l4 * 4 + r) * 64 + wq * 16 + l15] = o[n][r];
      if (l4 == 0) {
        mlb[wq * 16 + l15][0] = rm;
        mlb[wq * 16 + l15][1] = rl;
      }
    }
    __syncthreads();
    if (g == 0) {
      float m1 = mlb[wq * 16 + l15][0];
      float l1 = mlb[wq * 16 + l15][1];
      float mm = fmaxf(rm, m1);
      float w0 = __builtin_amdgcn_exp2f((rm - mm) * sl2);
      float w1 = __builtin_amdgcn_exp2f((m1 - mm) * sl2);
      float inv = 1.0f / (rl * w0 + l1 * w1);
      w0 *= inv; w1 *= inv;
      int qg = qt * 64 + wq * 16 + l15;
#pragma unroll
      for (int n = 0; n < 8; ++n) {
        f32x4 ov;
#pragma unroll
        for (int r = 0; r < 4; ++r) {
          float o1 = Mbuf[(n * 16 + l4 * 4 + r) * 64 + wq * 16 + l15];
          ov[r] = o[n][r] * w0 + o1 * w1;
        }
        *(f32x4*)(out + ((size_t)b * kMQ + qg) * kVC + h * 128 + n * 16 + l4 * 4) = ov;
      }
    }
  }
}

}  // namespace

extern "C" void kernel_launch(void* const* d_in, const int* in_sizes, int n_in,
                              void* d_out, int out_size, void* d_ws, size_t ws_size,
                              hipStream_t stream) {
  (void)in_sizes; (void)n_in; (void)out_size; (void)ws_size;
  const float* hs   = (const float*)d_in[0];
  const float* xin  = (const float*)d_in[1];
  const int*   msk  = (const int*)d_in[2];
  const float* ln1w = (const float*)d_in[3];
  const float* ln1b = (const float*)d_in[4];
  const float* ln2w = (const float*)d_in[5];
  const float* ln2b = (const float*)d_in[6];
  const float* Wq   = (const float*)d_in[7];
  const float* bq   = (const float*)d_in[8];
  const float* Wk   = (const float*)d_in[9];
  const float* bk   = (const float*)d_in[10];
  const float* Wv   = (const float*)d_in[11];
  const float* bv   = (const float*)d_in[12];
  float* out = (float*)d_out;

  char* ws = (char*)d_ws;
  _Float16* qbf  = (_Float16*)(ws + 0);          //  8,388,608 B [4096][1024]
  _Float16* kbf  = (_Float16*)(ws + 8388608);    // 33,554,432 B [16384][1024]
  _Float16* vT   = (_Float16*)(ws + 41943040);   // 33,554,432 B [1024][16384]
  _Float16* hsln = (_Float16*)(ws + 75497472);   //  8,388,608 B
  _Float16* kvln = (_Float16*)(ws + 83886080);   //  8,388,608 B
  _Float16* WqT  = (_Float16*)(ws + 92274688);   //  2,097,152 B [1024][1024]
  _Float16* WkT  = (_Float16*)(ws + 94371840);   //    524,288 B [1024][256]
  _Float16* WvT  = (_Float16*)(ws + 94896128);   //    524,288 B [1024][256]
  // total 95,420,416 B

  prep_all<<<8576, 256, 0, stream>>>(Wq, Wk, Wv, WqT, WkT, WvT,
                                     hs, ln1w, ln1b, hsln,
                                     xin, ln2w, ln2b, kvln);
  gemm_all<<<2304, 256, 0, stream>>>(hsln, WqT, bq, qbf,
                                     kvln, WkT, bk, kbf,
                                     WvT, bv, vT, msk);
  attn_kernel<<<256, 512, 0, stream>>>(qbf, kbf, vT, msk, out);
}

// Round 15
// 106.613 us; speedup vs baseline: 1.2531x; 1.2531x over previous
//
#include <hip/hip_runtime.h>

#define DI __device__ __forceinline__

typedef _Float16 f16x8 __attribute__((ext_vector_type(8)));
typedef _Float16 f16x4 __attribute__((ext_vector_type(4)));
typedef float    f32x4 __attribute__((ext_vector_type(4)));

namespace {

constexpr int kB  = 8;
constexpr int kMQ = 512;
constexpr int kMK = 2048;
constexpr int kQKC = 1024;   // = H*DQ
constexpr int kVC  = 1024;   // = H*DV

DI void gload16(const void* g, void* l) {
  __builtin_amdgcn_global_load_lds(
      (const __attribute__((address_space(1))) void*)g,
      (__attribute__((address_space(3))) void*)l, 16, 0, 0);
}

DI f32x4 mfma16(f16x8 a, f16x8 b, f32x4 c) {
  return __builtin_amdgcn_mfma_f32_16x16x32_f16(a, b, c, 0, 0, 0);
}

DI f32x4 mfma16k16(f16x4 a, f16x4 b, f32x4 c) {
  return __builtin_amdgcn_mfma_f32_16x16x16f16(a, b, c, 0, 0, 0);
}

// ================= unified prep: 3 weight transposes + 2 LayerNorms =================
template<int K, int N>
DI void transpose_dev(const float* __restrict__ W, _Float16* __restrict__ WT,
                      int bid, float (*t)[65]) {
  int nt = bid % (N / 64), kt = bid / (N / 64);
  int k0 = kt * 64, n0 = nt * 64;
  int tid = threadIdx.x;
#pragma unroll
  for (int j = 0; j < 16; ++j) {
    int e = tid + j * 256;
    int r = e >> 6, c = e & 63;
    t[r][c] = W[(size_t)(k0 + r) * N + n0 + c];
  }
  __syncthreads();
#pragma unroll
  for (int j = 0; j < 16; ++j) {
    int e = tid + j * 256;
    int r = e >> 6, c = e & 63;
    WT[(size_t)(n0 + r) * K + k0 + c] = (_Float16)t[c][r];
  }
}

DI void ln1024_dev(const float* __restrict__ x, const float* __restrict__ w,
                   const float* __restrict__ bb, _Float16* __restrict__ y,
                   int row, float* red) {
  int tid = threadIdx.x;
  const float4* xr = (const float4*)(x + (size_t)row * 1024);
  float4 v = xr[tid];
  float s = v.x + v.y + v.z + v.w;
  float q = v.x * v.x + v.y * v.y + v.z * v.z + v.w * v.w;
#pragma unroll
  for (int m = 32; m; m >>= 1) { s += __shfl_xor(s, m); q += __shfl_xor(q, m); }
  if ((tid & 63) == 0) { red[tid >> 6] = s; red[4 + (tid >> 6)] = q; }
  __syncthreads();
  s = red[0] + red[1] + red[2] + red[3];
  q = red[4] + red[5] + red[6] + red[7];
  float mean = s * (1.0f / 1024.0f);
  float var = q * (1.0f / 1024.0f) - mean * mean;
  float inv = rsqrtf(var + 1e-5f);
  f16x4 o;
  const float* wp = w + tid * 4;
  const float* bp = bb + tid * 4;
  o[0] = (_Float16)((v.x - mean) * inv * wp[0] + bp[0]);
  o[1] = (_Float16)((v.y - mean) * inv * wp[1] + bp[1]);
  o[2] = (_Float16)((v.z - mean) * inv * wp[2] + bp[2]);
  o[3] = (_Float16)((v.w - mean) * inv * wp[3] + bp[3]);
  *(f16x4*)(y + (size_t)row * 1024 + tid * 4) = o;
}

DI void ln256_dev(const float* __restrict__ x, const float* __restrict__ w,
                  const float* __restrict__ bb, _Float16* __restrict__ y, int bid) {
  int tid = threadIdx.x;
  int lane = tid & 63, wv = tid >> 6;
  size_t row = (size_t)bid * 4 + wv;
  const float4* xr = (const float4*)(x + row * 256);
  float4 v = xr[lane];
  float s = v.x + v.y + v.z + v.w;
  float q = v.x * v.x + v.y * v.y + v.z * v.z + v.w * v.w;
#pragma unroll
  for (int m = 32; m; m >>= 1) { s += __shfl_xor(s, m); q += __shfl_xor(q, m); }
  float mean = s * (1.0f / 256.0f);
  float var = q * (1.0f / 256.0f) - mean * mean;
  float inv = rsqrtf(var + 1e-5f);
  f16x4 o;
  const float* wp = w + lane * 4;
  const float* bp = bb + lane * 4;
  o[0] = (_Float16)((v.x - mean) * inv * wp[0] + bp[0]);
  o[1] = (_Float16)((v.y - mean) * inv * wp[1] + bp[1]);
  o[2] = (_Float16)((v.z - mean) * inv * wp[2] + bp[2]);
  o[3] = (_Float16)((v.w - mean) * inv * wp[3] + bp[3]);
  *(f16x4*)(y + row * 256 + lane * 4) = o;
}

__global__ __launch_bounds__(256) void prep_all(
    const float* __restrict__ Wq, const float* __restrict__ Wk, const float* __restrict__ Wv,
    _Float16* __restrict__ WqT, _Float16* __restrict__ WkT, _Float16* __restrict__ WvT,
    const float* __restrict__ hs, const float* __restrict__ ln1w, const float* __restrict__ ln1b,
    _Float16* __restrict__ hsln,
    const float* __restrict__ xin, const float* __restrict__ ln2w, const float* __restrict__ ln2b,
    _Float16* __restrict__ kvln) {
  __shared__ float tbuf[64][65];
  int bid = blockIdx.x;
  if (bid < 256) {
    transpose_dev<1024, 1024>(Wq, WqT, bid, tbuf);
  } else if (bid < 320) {
    transpose_dev<256, 1024>(Wk, WkT, bid - 256, tbuf);
  } else if (bid < 384) {
    transpose_dev<256, 1024>(Wv, WvT, bid - 320, tbuf);
  } else if (bid < 4480) {
    ln1024_dev(hs, ln1w, ln1b, hsln, bid - 384, (float*)tbuf);
  } else {
    ln256_dev(xin, ln2w, ln2b, kvln, bid - 4480);
  }
}

// ================= unified projection GEMM (CM decode for q/k A-panel L2 reuse) =====
template<int M, int N, int K, bool BIAS_ROW, int MMODE, bool CM>
DI void gemm_dev(const _Float16* __restrict__ A, const _Float16* __restrict__ Bt,
                 const float* __restrict__ bias, const int* __restrict__ msk,
                 _Float16* __restrict__ C, int bid,
                 _Float16 (*As)[128 * 64], _Float16 (*Bs)[128 * 64]) {
  int tid = threadIdx.x, lane = tid & 63;
  int w = tid >> 6, wr = w >> 1, wc = w & 1;
  constexpr int NT = N / 128;
  constexpr int MT = M / 128;
  constexpr int KT = K / 64;
  int mt, nt;
  if constexpr (CM) { mt = bid % MT; nt = bid / MT; }
  else              { mt = bid / NT; nt = bid % NT; }
  if constexpr (MMODE == 1) { if (msk[mt * 128] == 0) return; }
  if constexpr (MMODE == 2) { if (msk[nt * 128] == 0) return; }
  const int l15 = lane & 15, l4 = lane >> 4;

  f32x4 acc[4][4] = {};

  const int rS = tid >> 3;   // staging row (0..31) per 4KB call
  const int cpS = tid & 7;   // staging physical chunk

  auto stage = [&](int kt, int bufi) {
#pragma unroll
    for (int j = 0; j < 4; ++j) {
      int rr = rS + j * 32;
      int cg = cpS ^ (rr & 7);
      gload16(A  + ((size_t)(mt * 128 + rr) * K + kt * 64 + cg * 8),
              (char*)As[bufi] + j * 4096 + tid * 16);
      gload16(Bt + ((size_t)(nt * 128 + rr) * K + kt * 64 + cg * 8),
              (char*)Bs[bufi] + j * 4096 + tid * 16);
    }
  };

  stage(0, 0);
  __syncthreads();

  for (int kt = 0; kt < KT; ++kt) {
    int cur = kt & 1;
    if (kt + 1 < KT) stage(kt + 1, cur ^ 1);
#pragma unroll
    for (int ss = 0; ss < 2; ++ss) {
      f16x8 a[4], b[4];
#pragma unroll
      for (int m = 0; m < 4; ++m) {
        int ra = wr * 64 + m * 16 + l15;
        int cl = ss * 4 + l4;
        a[m] = *(const f16x8*)((const char*)As[cur] + ra * 128 + ((cl ^ (ra & 7)) << 4));
        int rb = wc * 64 + m * 16 + l15;
        b[m] = *(const f16x8*)((const char*)Bs[cur] + rb * 128 + ((cl ^ (rb & 7)) << 4));
      }
#pragma unroll
      for (int m = 0; m < 4; ++m)
#pragma unroll
        for (int n = 0; n < 4; ++n)
          acc[m][n] = mfma16(a[m], b[n], acc[m][n]);
    }
    __syncthreads();
  }

#pragma unroll
  for (int m = 0; m < 4; ++m) {
#pragma unroll
    for (int n = 0; n < 4; ++n) {
      int gi0 = mt * 128 + wr * 64 + m * 16 + l4 * 4;
      int gj  = nt * 128 + wc * 64 + n * 16 + l15;
#pragma unroll
      for (int r = 0; r < 4; ++r) {
        int gi = gi0 + r;
        float v = acc[m][n][r] + (BIAS_ROW ? bias[gi] : bias[gj]);
        C[(size_t)gi * N + gj] = (_Float16)v;
      }
    }
  }
}

__global__ __launch_bounds__(256) void gemm_all(
    const _Float16* __restrict__ hsln, const _Float16* __restrict__ WqT,
    const float* __restrict__ bq, _Float16* __restrict__ qbf,
    const _Float16* __restrict__ kvln, const _Float16* __restrict__ WkT,
    const float* __restrict__ bk, _Float16* __restrict__ kbf,
    const _Float16* __restrict__ WvT, const float* __restrict__ bv,
    _Float16* __restrict__ vT, const int* __restrict__ msk) {
  __shared__ _Float16 As[2][128 * 64];
  __shared__ _Float16 Bs[2][128 * 64];
  int bid = blockIdx.x;
  if (bid < 256) {
    gemm_dev<4096, 1024, 1024, false, 0, true>(hsln, WqT, bq, nullptr, qbf, bid, As, Bs);
  } else if (bid < 1280) {
    gemm_dev<16384, 1024, 256, false, 1, true>(kvln, WkT, bk, msk, kbf, bid - 256, As, Bs);
  } else {
    gemm_dev<1024, 16384, 256, true, 2, false>(WvT, kvln, bv, msk, vT, bid - 1280, As, Bs);
  }
}

// ============ fused masked flash attention (q-tile 128, K-tile 128, 8-wave) =========
// grid = 256: bh = blockIdx%64 (XCD locality), qt = blockIdx/64 (4 tiles of 128 q).
// 512 threads = 8 waves = 4 q-subtiles (32 rows) x 2 key-groups (64 keys each).
// K-tile 128: barriers and online-softmax bookkeeping amortize over 2x the keys of
// round 12 (the proven 71us kernel); MFMA volume and staged bytes per key unchanged.
// LDS 128KB: K dbuf 2x32KB + V dbuf 2x32KB. 1 block/CU.
// End-of-kernel merge of the 2 key-groups through LDS (block barrier, no fences).
__global__ __launch_bounds__(512, 2) void attn_kernel(const _Float16* __restrict__ qm,
                                                      const _Float16* __restrict__ km,
                                                      const _Float16* __restrict__ vT,
                                                      const int* __restrict__ msk,
                                                      float* __restrict__ out) {
  // overlay: [0,64KB) K dbuf, [64KB,128KB) V dbuf; after loop [0,64KB) = O~ scratch
  __shared__ __align__(16) char smem[132096];
  _Float16* Ksp = (_Float16*)smem;            // [2][128 key][128 d]  32KB each
  _Float16* Vsp = (_Float16*)(smem + 65536);  // [2][128 dv][128 key] 32KB each
  float*    mlb = (float*)(smem + 131072);    // [128 q][2]

  int tid = threadIdx.x, lane = tid & 63, w = tid >> 6;
  int bh = blockIdx.x & 63, qt = blockIdx.x >> 6;
  int h = bh & 7, b = bh >> 3;
  const int l15 = lane & 15, l4 = lane >> 4;
  const int wq = w & 3;        // q-subtile (0..3), rows qt*128 + wq*32 + m*16 + l15
  const int g  = w >> 2;       // key group (0..1), keys g*64 .. g*64+63

  // prefix mask: valid length L, number of 128-key tiles
  int vld = (lane < 32) ? msk[b * kMK + lane * 64] : 0;
  int nt64 = __popcll(__ballot(vld != 0));
  int lv = msk[b * kMK + (nt64 - 1) * 64 + lane];
  int L = (nt64 - 1) * 64 + __popcll(__ballot(lv != 0));
  int ntiles = (L + 127) >> 7;

  // Q fragments (B-operand): lane holds Q[q=qt*128+wq*32+m*16+l15][d=kc*32+l4*8+:8]
  f16x8 qf[2][4];
#pragma unroll
  for (int m = 0; m < 2; ++m)
#pragma unroll
    for (int kc = 0; kc < 4; ++kc)
      qf[m][kc] = *(const f16x8*)(qm +
          (size_t)(b * kMQ + qt * 128 + wq * 32 + m * 16 + l15) * kQKC +
          h * 128 + kc * 32 + l4 * 8);

  f32x4 o[2][8] = {};              // O^T partials: o[m][n][r] = O[dv=n*16+l4*4+r][q]
  float rm[2] = {-1e30f, -1e30f}, rl[2] = {0.0f, 0.0f};

  const float sl2 = 0.08838834764831845f * 1.4426950408889634f;  // scale * log2(e)

  const int rKV = tid >> 4, cp = tid & 15;   // staging: 32 rows/call, 16 chunks/row

  auto stage = [&](int kt, int bufi) {
#pragma unroll
    for (int j = 0; j < 4; ++j) {
      int rr = rKV + j * 32;
      int cg = cp ^ (rr & 7);
      gload16(km + (size_t)(b * kMK + kt * 128 + rr) * kQKC + h * 128 + cg * 8,
              (char*)Ksp + bufi * 32768 + j * 8192 + tid * 16);
    }
#pragma unroll
    for (int j = 0; j < 4; ++j) {
      int dv = rKV + j * 32;
      int cg = cp ^ (dv & 15);
      gload16(vT + (size_t)(h * 128 + dv) * (kB * kMK) + (size_t)b * kMK + kt * 128 + cg * 8,
              (char*)Vsp + bufi * 32768 + j * 8192 + tid * 16);
    }
  };

  stage(0, 0);
  __syncthreads();

  for (int kt = 0; kt < ntiles; ++kt) {
    int cur = kt & 1;
    if (kt + 1 < ntiles) stage(kt + 1, cur ^ 1);

    // S^T = mfma(K, Q): sc[m][kf] = S[key=g*64+kf*16+l4*4+r][q = m-frag, l15]
    f32x4 sc[2][4] = {};
    __builtin_amdgcn_s_setprio(1);
#pragma unroll
    for (int kc = 0; kc < 4; ++kc) {
      f16x8 kb[4];
#pragma unroll
      for (int kf = 0; kf < 4; ++kf) {
        int rr = g * 64 + kf * 16 + l15;
        int cl = kc * 4 + l4;
        kb[kf] = *(const f16x8*)((const char*)Ksp + cur * 32768 + rr * 256 +
                                 ((cl ^ (rr & 7)) << 4));
      }
#pragma unroll
      for (int m = 0; m < 2; ++m)
#pragma unroll
        for (int kf = 0; kf < 4; ++kf)
          sc[m][kf] = mfma16(kb[kf], qf[m][kc], sc[m][kf]);
    }
    __builtin_amdgcn_s_setprio(0);

    // tail mask on the final tile (raw-domain -inf surrogate)
    if (kt == ntiles - 1) {
      int base = kt * 128 + g * 64;
#pragma unroll
      for (int kf = 0; kf < 4; ++kf)
#pragma unroll
        for (int r = 0; r < 4; ++r)
          if (base + kf * 16 + l4 * 4 + r >= L) {
            sc[0][kf][r] = -3e38f;
            sc[1][kf][r] = -3e38f;
          }
    }

    // lane-parallel online softmax per q-fragment (one pass per 128 keys)
    float mx[2];
#pragma unroll
    for (int m = 0; m < 2; ++m) {
      float v = sc[m][0][0];
#pragma unroll
      for (int kf = 0; kf < 4; ++kf)
#pragma unroll
        for (int r = 0; r < 4; ++r) v = fmaxf(v, sc[m][kf][r]);
      v = fmaxf(v, __shfl_xor(v, 16));
      v = fmaxf(v, __shfl_xor(v, 32));
      mx[m] = v;
    }
    float al[2] = {1.0f, 1.0f};
    if (__any(mx[0] > rm[0] || mx[1] > rm[1])) {
#pragma unroll
      for (int m = 0; m < 2; ++m) {
        float nm = fmaxf(rm[m], mx[m]);
        al[m] = __builtin_amdgcn_exp2f((rm[m] - nm) * sl2);
        rm[m] = nm;
#pragma unroll
        for (int n = 0; n < 8; ++n)
#pragma unroll
          for (int r = 0; r < 4; ++r) o[m][n][r] *= al[m];
      }
    }
    f16x4 pb[2][4];
#pragma unroll
    for (int m = 0; m < 2; ++m) {
      float nms = rm[m] * sl2;
      float ts = 0.0f;
#pragma unroll
      for (int kf = 0; kf < 4; ++kf)
#pragma unroll
        for (int r = 0; r < 4; ++r) {
          float p = __builtin_amdgcn_exp2f(sc[m][kf][r] * sl2 - nms);
          pb[m][kf][r] = (_Float16)p;
          ts += p;
        }
      ts += __shfl_xor(ts, 16);
      ts += __shfl_xor(ts, 32);
      rl[m] = rl[m] * al[m] + ts;
    }

    // O^T += V^T P over this group's 64 keys; each vb read feeds both q-fragments
    __builtin_amdgcn_s_setprio(1);
#pragma unroll
    for (int n = 0; n < 8; ++n) {
      int dv = n * 16 + l15;
#pragma unroll
      for (int kf = 0; kf < 4; ++kf) {
        int phys = (g * 8 + kf * 2 + (l4 >> 1)) ^ (dv & 15);
        f16x4 vb = *(const f16x4*)((const char*)Vsp + cur * 32768 +
                                   dv * 256 + (phys << 4) + (l4 & 1) * 8);
#pragma unroll
        for (int m = 0; m < 2; ++m)
          o[m][n] = mfma16k16(vb, pb[m][kf], o[m][n]);
      }
    }
    __builtin_amdgcn_s_setprio(0);
    __syncthreads();
  }

  // ===== intra-block merge of the two key-groups (LDS, no fences) =====
  float* Mbuf = (float*)smem;   // [128 dv][128 q] f32 = 64KB (K buffers dead)
  if (g == 1) {
#pragma unroll
    for (int m = 0; m < 2; ++m) {
#pragma unroll
      for (int n = 0; n < 8; ++n)
#pragma unroll
        for (int r = 0; r < 4; ++r)
          Mbuf[(n * 16 + l4 * 4 + r) * 128 + wq * 32 + m * 16 + l15] = o[m][n][r];
      if (l4 == 0) {
        mlb[(wq * 32 + m * 16 + l15) * 2 + 0] = rm[m];
        mlb[(wq * 32 + m * 16 + l15) * 2 + 1] = rl[m];
      }
    }
  }
  __syncthreads();
  if (g == 1) return;

#pragma unroll
  for (int m = 0; m < 2; ++m) {
    int ql = wq * 32 + m * 16 + l15;
    float m1 = mlb[ql * 2 + 0];
    float l1 = mlb[ql * 2 + 1];
    float mm = fmaxf(rm[m], m1);
    float w0 = __builtin_amdgcn_exp2f((rm[m] - mm) * sl2);
    float w1 = __builtin_amdgcn_exp2f((m1 - mm) * sl2);
    float inv = 1.0f / (rl[m] * w0 + l1 * w1);
    w0 *= inv; w1 *= inv;
    int qg = qt * 128 + ql;
#pragma unroll
    for (int n = 0; n < 8; ++n) {
      f32x4 ov;
#pragma unroll
      for (int r = 0; r < 4; ++r) {
        float o1 = Mbuf[(n * 16 + l4 * 4 + r) * 128 + ql];
        ov[r] = o[m][n][r] * w0 + o1 * w1;
      }
      *(f32x4*)(out + ((size_t)b * kMQ + qg) * kVC + h * 128 + n * 16 + l4 * 4) = ov;
    }
  }
}

}  // namespace

extern "C" void kernel_launch(void* const* d_in, const int* in_sizes, int n_in,
                              void* d_out, int out_size, void* d_ws, size_t ws_size,
                              hipStream_t stream) {
  (void)in_sizes; (void)n_in; (void)out_size; (void)ws_size;
  const float* hs   = (const float*)d_in[0];
  const float* xin  = (const float*)d_in[1];
  const int*   msk  = (const int*)d_in[2];
  const float* ln1w = (const float*)d_in[3];
  const float* ln1b = (const float*)d_in[4];
  const float* ln2w = (const float*)d_in[5];
  const float* ln2b = (const float*)d_in[6];
  const float* Wq   = (const float*)d_in[7];
  const float* bq   = (const float*)d_in[8];
  const float* Wk   = (const float*)d_in[9];
  const float* bk   = (const float*)d_in[10];
  const float* Wv   = (const float*)d_in[11];
  const float* bv   = (const float*)d_in[12];
  float* out = (float*)d_out;

  char* ws = (char*)d_ws;
  _Float16* qbf  = (_Float16*)(ws + 0);          //  8,388,608 B [4096][1024]
  _Float16* kbf  = (_Float16*)(ws + 8388608);    // 33,554,432 B [16384][1024]
  _Float16* vT   = (_Float16*)(ws + 41943040);   // 33,554,432 B [1024][16384]
  _Float16* hsln = (_Float16*)(ws + 75497472);   //  8,388,608 B
  _Float16* kvln = (_Float16*)(ws + 83886080);   //  8,388,608 B
  _Float16* WqT  = (_Float16*)(ws + 92274688);   //  2,097,152 B [1024][1024]
  _Float16* WkT  = (_Float16*)(ws + 94371840);   //    524,288 B [1024][256]
  _Float16* WvT  = (_Float16*)(ws + 94896128);   //    524,288 B [1024][256]
  // total 95,420,416 B

  prep_all<<<8576, 256, 0, stream>>>(Wq, Wk, Wv, WqT, WkT, WvT,
                                     hs, ln1w, ln1b, hsln,
                                     xin, ln2w, ln2b, kvln);
  gemm_all<<<2304, 256, 0, stream>>>(hsln, WqT, bq, qbf,
                                     kvln, WkT, bk, kbf,
                                     WvT, bv, vT, msk);
  attn_kernel<<<256, 512, 0, stream>>>(qbf, kbf, vT, msk, out);
}